// Round 11
// baseline (128707.483 us; speedup 1.0000x reference)
//
#include <hip/hip_runtime.h>

// Vector quantization: z [32768,256] f32, codebook [8192,256] f32
// outputs: z_q [32768,256] f32, indices [32768] (as float)
//
// fp8-e4m3 MFMA screen (margin-bounded candidate superset, Bernstein-safe
// MARGIN) + exact resolve with the bitwise round-2 f32 chain (absmax 0 in
// rounds 2-10). Screen v6: fp8 halves registers (140/wave -> 3 waves/SIMD)
// and halves the codebook image (2 MB -> per-XCD L2 resident).
// Codebook pre-scaled by 2^13 (raw values are e4m3-subnormal); epilogue
// folds 2^-13 into the fmaf constant.

#define NROWS 32768
#define DIM   256
#define KCB   8192
#define CANDCAP 128
#define MARGIN  8.0e-3f
#define WBUF    320

// scratch byte offsets (from scratch base SB = d_ws or d_out)
#define SB_CAND  0u          // u16 [32768][128]  8 MB
#define SB_CNT   8388608u    // u32 [32768]
#define SB_ZSQ   8519680u    // f32 [32768]
#define SB_CSQ   8650752u    // f32 [8192]
#define SB_CSQ1  8683520u    // f32 [8192]
#define SB_OVL   8716288u    // u32 [32768]
#define SB_OVC   8847360u    // u32 (+pad)
#define SB_CBIMG 8847376u    // e4m3 cb image [512][4][64]x16B = 2 MB
#define SB_ZIMG  10944528u   // e4m3 z image [512][4][4][64]x16B = 8 MB
#define SB_NEED  19333136u

using f32x4 = __attribute__((ext_vector_type(4))) float;
typedef unsigned long long u64;

__device__ __forceinline__ unsigned f32_to_e4m3(float f) {
    unsigned u = __float_as_uint(f);
    unsigned sign = (u >> 24) & 0x80u;
    float af = fabsf(f);
    if (af >= 0.015625f) {                       // normal (e4m3 bias 7)
        unsigned r = u + 0x7FFFFu + ((u >> 20) & 1u);   // RNE to 3-bit mantissa
        unsigned e = (r >> 23) & 0xFFu;
        return sign | ((e - 120u) << 3) | ((r >> 20) & 7u);
    }
    int n = (int)rintf(af * 512.0f);             // subnormal: units of 2^-9
    return sign | (unsigned)n;                    // n==8 -> 2^-6, field-correct
}

__device__ __forceinline__ unsigned pack4_e4m3(float a, float b, float c, float d, float s) {
    return f32_to_e4m3(a * s) | (f32_to_e4m3(b * s) << 8) |
           (f32_to_e4m3(c * s) << 16) | (f32_to_e4m3(d * s) << 24);
}

// numpy pairwise sum of squares, n=256, bitwise-faithful (rounds 2-10).
__device__ float np_sumsq_256(const float* __restrict__ p) {
#pragma clang fp contract(off)
    float blk[2];
    #pragma unroll
    for (int b = 0; b < 2; ++b) {
        const float4* q4 = reinterpret_cast<const float4*>(p + b * 128);
        float4 a0 = q4[0], a1 = q4[1];
        float r[8];
        r[0] = __fmul_rn(a0.x, a0.x); r[1] = __fmul_rn(a0.y, a0.y);
        r[2] = __fmul_rn(a0.z, a0.z); r[3] = __fmul_rn(a0.w, a0.w);
        r[4] = __fmul_rn(a1.x, a1.x); r[5] = __fmul_rn(a1.y, a1.y);
        r[6] = __fmul_rn(a1.z, a1.z); r[7] = __fmul_rn(a1.w, a1.w);
        #pragma unroll
        for (int i = 2; i < 32; i += 2) {
            a0 = q4[i]; a1 = q4[i + 1];
            r[0] = __fadd_rn(r[0], __fmul_rn(a0.x, a0.x));
            r[1] = __fadd_rn(r[1], __fmul_rn(a0.y, a0.y));
            r[2] = __fadd_rn(r[2], __fmul_rn(a0.z, a0.z));
            r[3] = __fadd_rn(r[3], __fmul_rn(a0.w, a0.w));
            r[4] = __fadd_rn(r[4], __fmul_rn(a1.x, a1.x));
            r[5] = __fadd_rn(r[5], __fmul_rn(a1.y, a1.y));
            r[6] = __fadd_rn(r[6], __fmul_rn(a1.z, a1.z));
            r[7] = __fadd_rn(r[7], __fmul_rn(a1.w, a1.w));
        }
        blk[b] = __fadd_rn(
            __fadd_rn(__fadd_rn(r[0], r[1]), __fadd_rn(r[2], r[3])),
            __fadd_rn(__fadd_rn(r[4], r[5]), __fadd_rn(r[6], r[7])));
    }
    return __fadd_rn(blk[0], blk[1]);
}

// Fused prep: e4m3 cb image (x2^13) + e4m3 z image + csq/csq1 + zsq + init.
// Fragment rule (both images): record (.., lane) 16B = frags kk=2c2, 2c2+1;
// frag(kk)[j] = e4m3(src[lane&15-row][kk*32 + (lane>>4)*8 + j]).
__global__ void vq_prep_kernel(const float* __restrict__ z,
                               const float* __restrict__ cb,
                               char* __restrict__ cbimg, char* __restrict__ zimg,
                               float* __restrict__ zsq, float* __restrict__ csq,
                               float* __restrict__ csq1,
                               unsigned* __restrict__ cnt, unsigned* __restrict__ ovc) {
    int t = blockIdx.x * 256 + threadIdx.x;
    if (t < NROWS) cnt[t] = 0;
    if (t == 0) *ovc = 0;
    if (t < 131072) {                       // cb image: [T 512][c2 4][lane 64]
        int lane = t & 63, c2 = (t >> 6) & 3, T = t >> 8;
        int code = T * 16 + (lane & 15), lhi = lane >> 4;
        const float* sA = cb + (size_t)code * DIM + (2 * c2) * 32 + lhi * 8;
        float4 a0 = *reinterpret_cast<const float4*>(sA);
        float4 a1 = *reinterpret_cast<const float4*>(sA + 4);
        float4 b0 = *reinterpret_cast<const float4*>(sA + 32);
        float4 b1 = *reinterpret_cast<const float4*>(sA + 36);
        uint4 o;
        o.x = pack4_e4m3(a0.x, a0.y, a0.z, a0.w, 8192.0f);
        o.y = pack4_e4m3(a1.x, a1.y, a1.z, a1.w, 8192.0f);
        o.z = pack4_e4m3(b0.x, b0.y, b0.z, b0.w, 8192.0f);
        o.w = pack4_e4m3(b1.x, b1.y, b1.z, b1.w, 8192.0f);
        *reinterpret_cast<uint4*>(cbimg + (size_t)T * 4096 + c2 * 1024 + lane * 16) = o;
    } else if (t < 131072 + 524288) {       // z image: [rb 512][m 4][c2 4][lane 64]
        int r2 = t - 131072;
        int lane = r2 & 63, c2 = (r2 >> 6) & 3, m = (r2 >> 8) & 3, rb = r2 >> 10;
        int row = rb * 64 + m * 16 + (lane & 15), lhi = lane >> 4;
        const float* sA = z + (size_t)row * DIM + (2 * c2) * 32 + lhi * 8;
        float4 a0 = *reinterpret_cast<const float4*>(sA);
        float4 a1 = *reinterpret_cast<const float4*>(sA + 4);
        float4 b0 = *reinterpret_cast<const float4*>(sA + 32);
        float4 b1 = *reinterpret_cast<const float4*>(sA + 36);
        uint4 o;
        o.x = pack4_e4m3(a0.x, a0.y, a0.z, a0.w, 1.0f);
        o.y = pack4_e4m3(a1.x, a1.y, a1.z, a1.w, 1.0f);
        o.z = pack4_e4m3(b0.x, b0.y, b0.z, b0.w, 1.0f);
        o.w = pack4_e4m3(b1.x, b1.y, b1.z, b1.w, 1.0f);
        *reinterpret_cast<uint4*>(zimg + (size_t)rb * 16384 + m * 4096 + c2 * 1024 + lane * 16) = o;
    } else if (t < 131072 + 524288 + KCB) {
        int k = t - 131072 - 524288;
        float s = np_sumsq_256(cb + (size_t)k * DIM);
        csq[k] = s;
        csq1[k] = s + 1.0f;
    } else if (t < 131072 + 524288 + KCB + NROWS) {
        int r = t - 131072 - 524288 - KCB;
        zsq[r] = np_sumsq_256(z + (size_t)r * DIM);
    }
}

// ---------------- fp8 register-streamed MFMA screen ----------------
// Grid 512 x 256 thr (4 waves, 3 blocks/CU). Block: 64 rows x 8192 codes;
// wave wc: code-quarter (2048 codes = 128 tiles of 16). A in 64 regs (fp8),
// B double-buffered 2x16 regs, no loop barriers.
__global__ __launch_bounds__(256, 3) void vq_screen_kernel(
    const char* __restrict__ zimg, const char* __restrict__ cbimg,
    const float* __restrict__ csq1,
    unsigned* __restrict__ cnt, unsigned short* __restrict__ cand) {
    __shared__ unsigned runmin[64];
    __shared__ unsigned wcnt[4];
    __shared__ unsigned wbuf[4][WBUF];
    const int tid = threadIdx.x, lane = tid & 63, wid = tid >> 6;
    const int wc = wid;
    const int l15 = lane & 15, lhi = lane >> 4;
    const int rb = blockIdx.x, row0 = rb * 64;

    // A fragments from z image (coalesced, no conversion in-kernel)
    long ah[4][8];                                // 64 VGPRs
    {
        const char* zb = zimg + (size_t)rb * 16384 + lane * 16;
        #pragma unroll
        for (int m = 0; m < 4; ++m)
            #pragma unroll
            for (int c2 = 0; c2 < 4; ++c2) {
                uint4 v = *reinterpret_cast<const uint4*>(zb + m * 4096 + c2 * 1024);
                ah[m][2 * c2]     = (long)(((u64)v.y << 32) | v.x);
                ah[m][2 * c2 + 1] = (long)(((u64)v.w << 32) | v.z);
            }
    }

    if (tid < 64) runmin[tid] = 0x7F800000u;      // +inf (s'' > 0 -> uint-monotone)
    if (tid < 4) wcnt[tid] = 0;
    __syncthreads();                              // the only block barrier

    f32x4 acc[4];
    #pragma unroll
    for (int m = 0; m < 4; ++m) acc[m] = (f32x4){0.f, 0.f, 0.f, 0.f};

    const char*  gp = cbimg + (size_t)(wc * 128) * 4096 + (size_t)lane * 16;
    const float* cp = csq1 + wc * 2048 + l15;
    int codeb = wc * 2048 + l15;

    uint4 bA[4]; float csA;
    uint4 bB[4]; float csB;

    auto PUSH = [&](int lr, int code) {
        unsigned pi = atomicAdd(&wcnt[wid], 1u);
        if (pi < WBUF) wbuf[wid][pi] = ((unsigned)lr << 13) | (unsigned)code;
        else {
            int grow = row0 + lr;
            unsigned gs = atomicAdd(&cnt[grow], 1u);
            if (gs < CANDCAP) cand[(size_t)grow * CANDCAP + gs] = (unsigned short)code;
        }
    };

#define LOADR(bh, cs)                                                     \
    {                                                                     \
        _Pragma("unroll")                                                 \
        for (int c2 = 0; c2 < 4; ++c2)                                    \
            bh[c2] = *reinterpret_cast<const uint4*>(gp + c2 * 1024);     \
        cs = *cp;                                                         \
        gp += 4096; cp += 16;                                             \
    }

#define MFMAS(bh)                                                         \
    {                                                                     \
        _Pragma("unroll")                                                 \
        for (int c2 = 0; c2 < 4; ++c2) {                                  \
            long b0 = (long)(((u64)bh[c2].y << 32) | bh[c2].x);           \
            long b1 = (long)(((u64)bh[c2].w << 32) | bh[c2].z);           \
            _Pragma("unroll")                                             \
            for (int m = 0; m < 4; ++m)                                   \
                acc[m] = __builtin_amdgcn_mfma_f32_16x16x32_fp8_fp8(      \
                    ah[m][2 * c2], b0, acc[m], 0, 0, 0);                  \
            _Pragma("unroll")                                             \
            for (int m = 0; m < 4; ++m)                                   \
                acc[m] = __builtin_amdgcn_mfma_f32_16x16x32_fp8_fp8(      \
                    ah[m][2 * c2 + 1], b1, acc[m], 0, 0, 0);              \
        }                                                                 \
    }

// s'' = csq1 - 2*(acc/8192) = fmaf(acc, -2^-12, csq1); positive -> uint order
#define EPI(csv)                                                          \
    {                                                                     \
        _Pragma("unroll")                                                 \
        for (int m = 0; m < 4; ++m) {                                     \
            const int lr0 = m * 16 + lhi * 4;                             \
            uint4 rmb = *reinterpret_cast<const uint4*>(&runmin[lr0]);    \
            float s0 = fmaf(acc[m][0], -2.44140625e-4f, csv);             \
            float s1 = fmaf(acc[m][1], -2.44140625e-4f, csv);             \
            float s2 = fmaf(acc[m][2], -2.44140625e-4f, csv);             \
            float s3 = fmaf(acc[m][3], -2.44140625e-4f, csv);             \
            bool c0 = s0 < __uint_as_float(rmb.x) + MARGIN;               \
            bool c1 = s1 < __uint_as_float(rmb.y) + MARGIN;               \
            bool c2 = s2 < __uint_as_float(rmb.z) + MARGIN;               \
            bool c3 = s3 < __uint_as_float(rmb.w) + MARGIN;               \
            if (__any(c0 | c1 | c2 | c3)) {                               \
                if (c0) { if (s0 < __uint_as_float(rmb.x)) atomicMin(&runmin[lr0 + 0], __float_as_uint(s0)); PUSH(lr0 + 0, codeb); } \
                if (c1) { if (s1 < __uint_as_float(rmb.y)) atomicMin(&runmin[lr0 + 1], __float_as_uint(s1)); PUSH(lr0 + 1, codeb); } \
                if (c2) { if (s2 < __uint_as_float(rmb.z)) atomicMin(&runmin[lr0 + 2], __float_as_uint(s2)); PUSH(lr0 + 2, codeb); } \
                if (c3) { if (s3 < __uint_as_float(rmb.w)) atomicMin(&runmin[lr0 + 3], __float_as_uint(s3)); PUSH(lr0 + 3, codeb); } \
            }                                                             \
            acc[m] = (f32x4){0.f, 0.f, 0.f, 0.f};                         \
        }                                                                 \
        codeb += 16;                                                      \
    }

    LOADR(bA, csA);                  // tile 0
    LOADR(bB, csB);                  // tile 1
    MFMAS(bA);
    {   // tile 0: self-bound epilogue (runmin may still be +inf)
        #pragma unroll
        for (int m = 0; m < 4; ++m) {
            const int lr0 = m * 16 + lhi * 4;
            #pragma unroll
            for (int r = 0; r < 4; ++r) {
                float s2 = fmaf(acc[m][r], -2.44140625e-4f, csA);
                float sm = s2;
                sm = fminf(sm, __shfl_xor(sm, 1));
                sm = fminf(sm, __shfl_xor(sm, 2));
                sm = fminf(sm, __shfl_xor(sm, 4));
                sm = fminf(sm, __shfl_xor(sm, 8));
                if (l15 == 0) atomicMin(&runmin[lr0 + r], __float_as_uint(sm));
                if (s2 < sm + MARGIN) PUSH(lr0 + r, codeb);
            }
            acc[m] = (f32x4){0.f, 0.f, 0.f, 0.f};
        }
        codeb += 16;
    }

    for (int t = 1; t < 127; t += 2) {
        LOADR(bA, csA);  MFMAS(bB);  EPI(csB);   // tile t,   load t+1
        LOADR(bB, csB);  MFMAS(bA);  EPI(csA);   // tile t+1, load t+2
    }
    MFMAS(bB);  EPI(csB);                        // tile 127

    // flush wave-local candidate buffer to global per-row lists
    unsigned n = wcnt[wid]; if (n > WBUF) n = WBUF;
    for (unsigned e = lane; e < n; e += 64) {
        unsigned u = wbuf[wid][e];
        int row = row0 + (int)(u >> 13);
        int code = (int)(u & 8191u);
        unsigned slot = atomicAdd(&cnt[row], 1u);
        if (slot < CANDCAP) cand[(size_t)row * CANDCAP + slot] = (unsigned short)code;
    }
#undef LOADR
#undef MFMAS
#undef EPI
}

// ---------------- exact resolve (rounds 6-10 chain) + fused gather ----------
__global__ __launch_bounds__(256) void vq_exact_kernel(
    const float* __restrict__ z, const float* __restrict__ cb,
    const float* __restrict__ zsq, const float* __restrict__ csq,
    const unsigned* __restrict__ cnt, const unsigned short* __restrict__ cand,
    unsigned* __restrict__ ovl, unsigned* __restrict__ ovc,
    float* __restrict__ idxF, float4* __restrict__ outz, int fused) {
    __shared__ float zrow[4][DIM];
    const int wid = threadIdx.x >> 6, lane = threadIdx.x & 63;
    const int row = blockIdx.x * 4 + wid;

    float4 zv4 = *reinterpret_cast<const float4*>(&z[(size_t)row * DIM + lane * 4]);
    *reinterpret_cast<float4*>(&zrow[wid][lane * 4]) = zv4;
    __syncthreads();

    const unsigned c = cnt[row];
    if (c == 0 || c > CANDCAP) {
        if (lane == 0) { unsigned s = atomicAdd(ovc, 1u); ovl[s] = row; }
        return;
    }

    const float Zr = zsq[row];
    const float4* cb4 = reinterpret_cast<const float4*>(cb);
    float best = 3.4e38f;
    int   bi   = 0x7FFFFFFF;

    for (int j = lane; j < (int)c; j += 64) {
        int k = cand[(size_t)row * CANDCAP + j];
        float a = 0.0f;
        #pragma unroll 8
        for (int q = 0; q < 64; ++q) {
            float4 cv = cb4[(size_t)k * 64 + q];
            float4 zv = *reinterpret_cast<const float4*>(&zrow[wid][q * 4]);
            a = fmaf(zv.x, cv.x, a); a = fmaf(zv.y, cv.y, a);
            a = fmaf(zv.z, cv.z, a); a = fmaf(zv.w, cv.w, a);
        }
        float sv = __fadd_rn(__fsub_rn(Zr, __fmul_rn(2.0f, a)), csq[k]);
        if (sv < best || (sv == best && k < bi)) { best = sv; bi = k; }
    }
    #pragma unroll
    for (int mk = 32; mk >= 1; mk >>= 1) {
        float ov = __shfl_xor(best, mk);
        int   oi = __shfl_xor(bi, mk);
        if (ov < best || (ov == best && oi < bi)) { best = ov; bi = oi; }
    }
    if (lane == 0) idxF[row] = (float)bi;
    if (fused) outz[(size_t)row * 64 + lane] = cb4[(size_t)bi * 64 + lane];
}

// Full scan for overflow rows (expected 0). Bitwise chain, first-index ties.
__global__ __launch_bounds__(256) void vq_cleanup_kernel(
    const float* __restrict__ z, const float* __restrict__ cb,
    const float* __restrict__ zsq, const float* __restrict__ csq,
    const unsigned* __restrict__ ovl, const unsigned* __restrict__ ovc,
    float* __restrict__ idxF, float4* __restrict__ outz, int fused) {
    __shared__ float zrow[DIM];
    __shared__ float wv[4]; __shared__ int wi[4];
    __shared__ int sbi;
    const int lane = threadIdx.x & 63, wid = threadIdx.x >> 6;
    const unsigned count = *ovc;
    for (unsigned w = blockIdx.x; w < count; w += gridDim.x) {
        const int row = ovl[w];
        __syncthreads();
        *reinterpret_cast<float4*>(&zrow[threadIdx.x * 4 & (DIM - 1)]) =
            *reinterpret_cast<const float4*>(&z[(size_t)row * DIM + (threadIdx.x * 4 & (DIM - 1))]);
        __syncthreads();
        const float Zr = zsq[row];
        const float4* cb4 = reinterpret_cast<const float4*>(cb);
        float best = 3.4e38f; int bi = 0x7FFFFFFF;
        for (int k = threadIdx.x; k < KCB; k += 256) {
            float a = 0.0f;
            #pragma unroll 8
            for (int q = 0; q < 64; ++q) {
                float4 cv = cb4[(size_t)k * 64 + q];
                float4 zv = *reinterpret_cast<const float4*>(&zrow[q * 4]);
                a = fmaf(zv.x, cv.x, a); a = fmaf(zv.y, cv.y, a);
                a = fmaf(zv.z, cv.z, a); a = fmaf(zv.w, cv.w, a);
            }
            float sv = __fadd_rn(__fsub_rn(Zr, __fmul_rn(2.0f, a)), csq[k]);
            if (sv < best || (sv == best && k < bi)) { best = sv; bi = k; }
        }
        #pragma unroll
        for (int mk = 32; mk >= 1; mk >>= 1) {
            float ov = __shfl_xor(best, mk);
            int   oi = __shfl_xor(bi, mk);
            if (ov < best || (ov == best && oi < bi)) { best = ov; bi = oi; }
        }
        if (lane == 0) { wv[wid] = best; wi[wid] = bi; }
        __syncthreads();
        if (threadIdx.x == 0) {
            #pragma unroll
            for (int u = 1; u < 4; ++u)
                if (wv[u] < best || (wv[u] == best && wi[u] < bi)) { best = wv[u]; bi = wi[u]; }
            idxF[row] = (float)bi;
            sbi = bi;
        }
        __syncthreads();
        if (fused && threadIdx.x < 64)
            outz[(size_t)row * 64 + threadIdx.x] = cb4[(size_t)sbi * 64 + threadIdx.x];
    }
}

__global__ void vq_gather_kernel(const float* __restrict__ cb,
                                 const float* __restrict__ idxF,
                                 float4* __restrict__ out4) {
    int g = blockIdx.x * blockDim.x + threadIdx.x;
    const float4* cb4 = reinterpret_cast<const float4*>(cb);
    for (int i = g; i < NROWS * 64; i += gridDim.x * blockDim.x) {
        int row = i >> 6, q = i & 63;
        int idx = (int)idxF[row];
        out4[i] = cb4[(size_t)idx * 64 + q];
    }
}

extern "C" void kernel_launch(void* const* d_in, const int* in_sizes, int n_in,
                              void* d_out, int out_size, void* d_ws, size_t ws_size,
                              hipStream_t stream) {
    const float* z  = (const float*)d_in[0];
    const float* cb = (const float*)d_in[1];
    float* out = (float*)d_out;

    const int fused = (ws_size >= (size_t)SB_NEED) ? 1 : 0;
    char* SB = fused ? (char*)d_ws : (char*)d_out;

    unsigned short* candp = (unsigned short*)(SB + SB_CAND);
    unsigned*       cntp  = (unsigned*)(SB + SB_CNT);
    float*          zsq   = (float*)(SB + SB_ZSQ);
    float*          csq   = (float*)(SB + SB_CSQ);
    float*          csq1  = (float*)(SB + SB_CSQ1);
    unsigned*       ovl   = (unsigned*)(SB + SB_OVL);
    unsigned*       ovc   = (unsigned*)(SB + SB_OVC);
    char*           cbimg = SB + SB_CBIMG;
    char*           zimg  = SB + SB_ZIMG;
    float*          idxF  = out + 8388608;   // output 1 (indices as float)

    vq_prep_kernel<<<(131072 + 524288 + KCB + NROWS + 255) / 256, 256, 0, stream>>>(
        z, cb, cbimg, zimg, zsq, csq, csq1, cntp, ovc);
    vq_screen_kernel<<<NROWS / 64, 256, 0, stream>>>(zimg, cbimg, csq1, cntp, candp);
    vq_exact_kernel<<<NROWS / 4, 256, 0, stream>>>(
        z, cb, zsq, csq, cntp, candp, ovl, ovc, idxF, (float4*)out, fused);
    vq_cleanup_kernel<<<64, 256, 0, stream>>>(
        z, cb, zsq, csq, ovl, ovc, idxF, (float4*)out, fused);
    if (!fused)
        vq_gather_kernel<<<2048, 256, 0, stream>>>(cb, idxF, (float4*)out);
}

// Round 13
// 413.109 us; speedup vs baseline: 311.5583x; 311.5583x over previous
//
#include <hip/hip_runtime.h>

// Vector quantization: z [32768,256] f32, codebook [8192,256] f32
// outputs: z_q [32768,256] f32, indices [32768] (as float)
//
// bf16 MFMA screen (MARGIN=4.5e-4, proven rounds 6-10) + exact resolve with
// the bitwise round-2 f32 chain (absmax 0 in rounds 2-11).
// Screen v7: 32 rows/wave (A=64 VGPR -> 3 waves/SIMD), XCD-parity K-split
// (per-XCD L2 holds a 2 MB codebook-image half), nt loads for read-once z.
// (Round 12 fix: nontemporal builtins need ext_vector_type, not HIP uint4.)

#define NROWS 32768
#define DIM   256
#define KCB   8192
#define CANDCAP 128
#define MARGIN  4.5e-4f
#define WBUF    320

// scratch byte offsets (from scratch base SB = d_ws or d_out)
#define SB_CAND  0u          // u16 [32768][128]  8 MB
#define SB_CNT   8388608u    // u32 [32768]
#define SB_ZSQ   8519680u    // f32 [32768]
#define SB_CSQ   8650752u    // f32 [8192]
#define SB_CSQ1  8683520u    // f32 [8192]
#define SB_OVL   8716288u    // u32 [32768]
#define SB_OVC   8847360u    // u32 (+pad)
#define SB_CBIMG 8847376u    // bf16 cb image [T 512][kk 8][lane 64]x16B = 4 MB
#define SB_ZIMG  13041680u   // bf16 z image [rb 512][wr 2][m 2][kk 8][lane 64]x16B = 16 MB
#define SB_NEED  29818896u

using bf16x8 = __attribute__((ext_vector_type(8))) short;
using f32x4  = __attribute__((ext_vector_type(4))) float;
using u32x4  = __attribute__((ext_vector_type(4))) unsigned int;

__device__ __forceinline__ unsigned short bf16rne(float f) {
    unsigned u = __float_as_uint(f);
    unsigned r = u + 0x7FFFu + ((u >> 16) & 1u);
    return (unsigned short)(r >> 16);
}

__device__ __forceinline__ unsigned pack2_bf16(float a, float b) {
    return (unsigned)bf16rne(a) | ((unsigned)bf16rne(b) << 16);
}

// numpy pairwise sum of squares, n=256, bitwise-faithful (rounds 2-11).
__device__ float np_sumsq_256(const float* __restrict__ p) {
#pragma clang fp contract(off)
    float blk[2];
    #pragma unroll
    for (int b = 0; b < 2; ++b) {
        const float4* q4 = reinterpret_cast<const float4*>(p + b * 128);
        float4 a0 = q4[0], a1 = q4[1];
        float r[8];
        r[0] = __fmul_rn(a0.x, a0.x); r[1] = __fmul_rn(a0.y, a0.y);
        r[2] = __fmul_rn(a0.z, a0.z); r[3] = __fmul_rn(a0.w, a0.w);
        r[4] = __fmul_rn(a1.x, a1.x); r[5] = __fmul_rn(a1.y, a1.y);
        r[6] = __fmul_rn(a1.z, a1.z); r[7] = __fmul_rn(a1.w, a1.w);
        #pragma unroll
        for (int i = 2; i < 32; i += 2) {
            a0 = q4[i]; a1 = q4[i + 1];
            r[0] = __fadd_rn(r[0], __fmul_rn(a0.x, a0.x));
            r[1] = __fadd_rn(r[1], __fmul_rn(a0.y, a0.y));
            r[2] = __fadd_rn(r[2], __fmul_rn(a0.z, a0.z));
            r[3] = __fadd_rn(r[3], __fmul_rn(a0.w, a0.w));
            r[4] = __fadd_rn(r[4], __fmul_rn(a1.x, a1.x));
            r[5] = __fadd_rn(r[5], __fmul_rn(a1.y, a1.y));
            r[6] = __fadd_rn(r[6], __fmul_rn(a1.z, a1.z));
            r[7] = __fadd_rn(r[7], __fmul_rn(a1.w, a1.w));
        }
        blk[b] = __fadd_rn(
            __fadd_rn(__fadd_rn(r[0], r[1]), __fadd_rn(r[2], r[3])),
            __fadd_rn(__fadd_rn(r[4], r[5]), __fadd_rn(r[6], r[7])));
    }
    return __fadd_rn(blk[0], blk[1]);
}

// Fused prep: bf16 cb image + bf16 z image + csq/csq1 + zsq + counter init.
// Fragment rule (both): record 16B = bf16x8 of src[row(lane&15)][kk*32+(lane>>4)*8..+8)
__global__ void vq_prep_kernel(const float* __restrict__ z,
                               const float* __restrict__ cb,
                               char* __restrict__ cbimg, char* __restrict__ zimg,
                               float* __restrict__ zsq, float* __restrict__ csq,
                               float* __restrict__ csq1,
                               unsigned* __restrict__ cnt, unsigned* __restrict__ ovc) {
    int t = blockIdx.x * 256 + threadIdx.x;
    if (t < NROWS) cnt[t] = 0;
    if (t == 0) *ovc = 0;
    if (t < 262144) {                         // cb image [T 512][kk 8][lane 64]
        int lane = t & 63, kk = (t >> 6) & 7, T = t >> 9;
        int code = T * 16 + (lane & 15);
        const float* src = cb + (size_t)code * DIM + kk * 32 + (lane >> 4) * 8;
        float4 v0 = *reinterpret_cast<const float4*>(src);
        float4 v1 = *reinterpret_cast<const float4*>(src + 4);
        uint4 o;
        o.x = pack2_bf16(v0.x, v0.y); o.y = pack2_bf16(v0.z, v0.w);
        o.z = pack2_bf16(v1.x, v1.y); o.w = pack2_bf16(v1.z, v1.w);
        *reinterpret_cast<uint4*>(cbimg + (size_t)t * 16) = o;
    } else if (t < 262144 + 1048576) {        // z image [rb 512][wr 2][m 2][kk 8][lane 64]
        int r = t - 262144;
        int lane = r & 63, kk = (r >> 6) & 7, m = (r >> 9) & 1, wr = (r >> 10) & 1, rb = r >> 11;
        int row = rb * 64 + wr * 32 + m * 16 + (lane & 15);
        const float* src = z + (size_t)row * DIM + kk * 32 + (lane >> 4) * 8;
        float4 v0 = *reinterpret_cast<const float4*>(src);
        float4 v1 = *reinterpret_cast<const float4*>(src + 4);
        uint4 o;
        o.x = pack2_bf16(v0.x, v0.y); o.y = pack2_bf16(v0.z, v0.w);
        o.z = pack2_bf16(v1.x, v1.y); o.w = pack2_bf16(v1.z, v1.w);
        *reinterpret_cast<uint4*>(zimg + (size_t)r * 16) = o;
    } else if (t < 262144 + 1048576 + KCB) {
        int k = t - 262144 - 1048576;
        float s = np_sumsq_256(cb + (size_t)k * DIM);
        csq[k] = s;
        csq1[k] = s + 1.0f;
    } else if (t < 262144 + 1048576 + KCB + NROWS) {
        int r = t - 262144 - 1048576 - KCB;
        zsq[r] = np_sumsq_256(z + (size_t)r * DIM);
    }
}

// ---------------- bf16 register-streamed MFMA screen, XCD-parity K-split ----
// Grid 1024 (ks=bid&1 -> XCD parity, rb=bid>>1) x 256 thr (4 waves, 3 blk/CU).
// Wave (wr,wc): 32 rows x 2048 codes as 128 tiles of 16 codes.
// A (32 rows) in 64 VGPRs from zimg (nt); B double-buffered 2x8 uint4.
__global__ __launch_bounds__(256, 3) void vq_screen_kernel(
    const char* __restrict__ zimg, const char* __restrict__ cbimg,
    const float* __restrict__ csq1,
    unsigned* __restrict__ cnt, unsigned short* __restrict__ cand) {
    __shared__ unsigned runmin[64];
    __shared__ unsigned wcnt[4];
    __shared__ unsigned wbuf[4][WBUF];
    const int tid = threadIdx.x, lane = tid & 63, wid = tid >> 6;
    const int wr = wid >> 1, wc = wid & 1;
    const int l15 = lane & 15, lhi = lane >> 4;
    const int bid = blockIdx.x, ks = bid & 1, rb = bid >> 1;
    const int row0 = rb * 64;
    const int Tstart = ks * 256 + wc * 128;

    // A fragments from z image (nt: read-once, keep cb image L2-resident)
    bf16x8 ah[2][8];                              // 64 VGPRs
    {
        const char* zb = zimg + (size_t)rb * 32768 + wr * 16384 + lane * 16;
        #pragma unroll
        for (int m = 0; m < 2; ++m)
            #pragma unroll
            for (int kk = 0; kk < 8; ++kk) {
                u32x4 v = __builtin_nontemporal_load(
                    reinterpret_cast<const u32x4*>(zb + m * 8192 + kk * 1024));
                ah[m][kk] = __builtin_bit_cast(bf16x8, v);
            }
    }

    if (tid < 64) runmin[tid] = 0x7F800000u;      // +inf (s'' > 0 -> uint-monotone)
    if (tid < 4) wcnt[tid] = 0;
    __syncthreads();                              // the only block barrier

    f32x4 acc[2];
    acc[0] = (f32x4){0.f, 0.f, 0.f, 0.f};
    acc[1] = (f32x4){0.f, 0.f, 0.f, 0.f};

    const char*  gp = cbimg + (size_t)Tstart * 8192 + (size_t)lane * 16;
    const float* cp = csq1 + Tstart * 16 + l15;
    int codeb = Tstart * 16 + l15;

    u32x4 bA[8]; float csA;
    u32x4 bB[8]; float csB;

    auto PUSH = [&](int lr, int code) {
        unsigned pi = atomicAdd(&wcnt[wid], 1u);
        if (pi < WBUF) wbuf[wid][pi] = ((unsigned)lr << 13) | (unsigned)code;
        else {
            int grow = row0 + lr;
            unsigned gs = atomicAdd(&cnt[grow], 1u);
            if (gs < CANDCAP) cand[(size_t)grow * CANDCAP + gs] = (unsigned short)code;
        }
    };

#define LOADR(bh, cs)                                                     \
    {                                                                     \
        _Pragma("unroll")                                                 \
        for (int kk = 0; kk < 8; ++kk)                                    \
            bh[kk] = *reinterpret_cast<const u32x4*>(gp + kk * 1024);     \
        cs = *cp;                                                         \
        gp += 8192; cp += 16;                                             \
    }

#define MFMAS(bh)                                                         \
    {                                                                     \
        _Pragma("unroll")                                                 \
        for (int kk = 0; kk < 8; ++kk) {                                  \
            bf16x8 bv = __builtin_bit_cast(bf16x8, bh[kk]);               \
            acc[0] = __builtin_amdgcn_mfma_f32_16x16x32_bf16(ah[0][kk], bv, acc[0], 0, 0, 0); \
            acc[1] = __builtin_amdgcn_mfma_f32_16x16x32_bf16(ah[1][kk], bv, acc[1], 0, 0, 0); \
        }                                                                 \
    }

#define EPI(csv)                                                          \
    {                                                                     \
        _Pragma("unroll")                                                 \
        for (int m = 0; m < 2; ++m) {                                     \
            const int lr0 = wr * 32 + m * 16 + lhi * 4;                   \
            uint4 rmb = *reinterpret_cast<const uint4*>(&runmin[lr0]);    \
            float s0 = fmaf(acc[m][0], -2.0f, csv);                       \
            float s1 = fmaf(acc[m][1], -2.0f, csv);                       \
            float s2 = fmaf(acc[m][2], -2.0f, csv);                       \
            float s3 = fmaf(acc[m][3], -2.0f, csv);                       \
            bool c0 = s0 < __uint_as_float(rmb.x) + MARGIN;               \
            bool c1 = s1 < __uint_as_float(rmb.y) + MARGIN;               \
            bool c2 = s2 < __uint_as_float(rmb.z) + MARGIN;               \
            bool c3 = s3 < __uint_as_float(rmb.w) + MARGIN;               \
            if (__any(c0 | c1 | c2 | c3)) {                               \
                if (c0) { if (s0 < __uint_as_float(rmb.x)) atomicMin(&runmin[lr0 + 0], __float_as_uint(s0)); PUSH(lr0 + 0, codeb); } \
                if (c1) { if (s1 < __uint_as_float(rmb.y)) atomicMin(&runmin[lr0 + 1], __float_as_uint(s1)); PUSH(lr0 + 1, codeb); } \
                if (c2) { if (s2 < __uint_as_float(rmb.z)) atomicMin(&runmin[lr0 + 2], __float_as_uint(s2)); PUSH(lr0 + 2, codeb); } \
                if (c3) { if (s3 < __uint_as_float(rmb.w)) atomicMin(&runmin[lr0 + 3], __float_as_uint(s3)); PUSH(lr0 + 3, codeb); } \
            }                                                             \
            acc[m] = (f32x4){0.f, 0.f, 0.f, 0.f};                        \
        }                                                                 \
        codeb += 16;                                                      \
    }

    LOADR(bA, csA);                  // tile 0
    LOADR(bB, csB);                  // tile 1
    MFMAS(bA);
    {   // tile 0: self-bound epilogue (runmin may still be +inf)
        #pragma unroll
        for (int m = 0; m < 2; ++m) {
            const int lr0 = wr * 32 + m * 16 + lhi * 4;
            #pragma unroll
            for (int r = 0; r < 4; ++r) {
                float s2 = fmaf(acc[m][r], -2.0f, csA);
                float sm = s2;
                sm = fminf(sm, __shfl_xor(sm, 1));
                sm = fminf(sm, __shfl_xor(sm, 2));
                sm = fminf(sm, __shfl_xor(sm, 4));
                sm = fminf(sm, __shfl_xor(sm, 8));
                if (l15 == 0) atomicMin(&runmin[lr0 + r], __float_as_uint(sm));
                if (s2 < sm + MARGIN) PUSH(lr0 + r, codeb);
            }
            acc[m] = (f32x4){0.f, 0.f, 0.f, 0.f};
        }
        codeb += 16;
    }

    for (int t = 1; t < 127; t += 2) {
        LOADR(bA, csA);  MFMAS(bB);  EPI(csB);   // tile t,   load t+1
        LOADR(bB, csB);  MFMAS(bA);  EPI(csA);   // tile t+1, load t+2
    }
    MFMAS(bB);  EPI(csB);                        // tile 127

    // flush wave-local candidate buffer to global per-row lists
    unsigned n = wcnt[wid]; if (n > WBUF) n = WBUF;
    for (unsigned e = lane; e < n; e += 64) {
        unsigned u = wbuf[wid][e];
        int row = row0 + (int)(u >> 13);
        int code = (int)(u & 8191u);
        unsigned slot = atomicAdd(&cnt[row], 1u);
        if (slot < CANDCAP)
            __builtin_nontemporal_store((unsigned short)code,
                                        &cand[(size_t)row * CANDCAP + slot]);
    }
#undef LOADR
#undef MFMAS
#undef EPI
}

// ---------------- exact resolve (rounds 6-11 chain) + fused gather ----------
__global__ __launch_bounds__(256) void vq_exact_kernel(
    const float* __restrict__ z, const float* __restrict__ cb,
    const float* __restrict__ zsq, const float* __restrict__ csq,
    const unsigned* __restrict__ cnt, const unsigned short* __restrict__ cand,
    unsigned* __restrict__ ovl, unsigned* __restrict__ ovc,
    float* __restrict__ idxF, float4* __restrict__ outz, int fused) {
    __shared__ float zrow[4][DIM];
    const int wid = threadIdx.x >> 6, lane = threadIdx.x & 63;
    const int row = blockIdx.x * 4 + wid;

    float4 zv4 = *reinterpret_cast<const float4*>(&z[(size_t)row * DIM + lane * 4]);
    *reinterpret_cast<float4*>(&zrow[wid][lane * 4]) = zv4;
    __syncthreads();

    const unsigned c = cnt[row];
    if (c == 0 || c > CANDCAP) {
        if (lane == 0) { unsigned s = atomicAdd(ovc, 1u); ovl[s] = row; }
        return;
    }

    const float Zr = zsq[row];
    const float4* cb4 = reinterpret_cast<const float4*>(cb);
    float best = 3.4e38f;
    int   bi   = 0x7FFFFFFF;

    for (int j = lane; j < (int)c; j += 64) {
        int k = cand[(size_t)row * CANDCAP + j];
        float a = 0.0f;
        #pragma unroll 8
        for (int q = 0; q < 64; ++q) {
            float4 cv = cb4[(size_t)k * 64 + q];
            float4 zv = *reinterpret_cast<const float4*>(&zrow[wid][q * 4]);
            a = fmaf(zv.x, cv.x, a); a = fmaf(zv.y, cv.y, a);
            a = fmaf(zv.z, cv.z, a); a = fmaf(zv.w, cv.w, a);
        }
        float sv = __fadd_rn(__fsub_rn(Zr, __fmul_rn(2.0f, a)), csq[k]);
        if (sv < best || (sv == best && k < bi)) { best = sv; bi = k; }
    }
    #pragma unroll
    for (int mk = 32; mk >= 1; mk >>= 1) {
        float ov = __shfl_xor(best, mk);
        int   oi = __shfl_xor(bi, mk);
        if (ov < best || (ov == best && oi < bi)) { best = ov; bi = oi; }
    }
    if (lane == 0) idxF[row] = (float)bi;
    if (fused) outz[(size_t)row * 64 + lane] = cb4[(size_t)bi * 64 + lane];
}

// Full scan for overflow rows (expected 0). Bitwise chain, first-index ties.
__global__ __launch_bounds__(256) void vq_cleanup_kernel(
    const float* __restrict__ z, const float* __restrict__ cb,
    const float* __restrict__ zsq, const float* __restrict__ csq,
    const unsigned* __restrict__ ovl, const unsigned* __restrict__ ovc,
    float* __restrict__ idxF, float4* __restrict__ outz, int fused) {
    __shared__ float zrow[DIM];
    __shared__ float wv[4]; __shared__ int wi[4];
    __shared__ int sbi;
    const int lane = threadIdx.x & 63, wid = threadIdx.x >> 6;
    const unsigned count = *ovc;
    for (unsigned w = blockIdx.x; w < count; w += gridDim.x) {
        const int row = ovl[w];
        __syncthreads();
        *reinterpret_cast<float4*>(&zrow[threadIdx.x * 4 & (DIM - 1)]) =
            *reinterpret_cast<const float4*>(&z[(size_t)row * DIM + (threadIdx.x * 4 & (DIM - 1))]);
        __syncthreads();
        const float Zr = zsq[row];
        const float4* cb4 = reinterpret_cast<const float4*>(cb);
        float best = 3.4e38f; int bi = 0x7FFFFFFF;
        for (int k = threadIdx.x; k < KCB; k += 256) {
            float a = 0.0f;
            #pragma unroll 8
            for (int q = 0; q < 64; ++q) {
                float4 cv = cb4[(size_t)k * 64 + q];
                float4 zv = *reinterpret_cast<const float4*>(&zrow[q * 4]);
                a = fmaf(zv.x, cv.x, a); a = fmaf(zv.y, cv.y, a);
                a = fmaf(zv.z, cv.z, a); a = fmaf(zv.w, cv.w, a);
            }
            float sv = __fadd_rn(__fsub_rn(Zr, __fmul_rn(2.0f, a)), csq[k]);
            if (sv < best || (sv == best && k < bi)) { best = sv; bi = k; }
        }
        #pragma unroll
        for (int mk = 32; mk >= 1; mk >>= 1) {
            float ov = __shfl_xor(best, mk);
            int   oi = __shfl_xor(bi, mk);
            if (ov < best || (ov == best && oi < bi)) { best = ov; bi = oi; }
        }
        if (lane == 0) { wv[wid] = best; wi[wid] = bi; }
        __syncthreads();
        if (threadIdx.x == 0) {
            #pragma unroll
            for (int u = 1; u < 4; ++u)
                if (wv[u] < best || (wv[u] == best && wi[u] < bi)) { best = wv[u]; bi = wi[u]; }
            idxF[row] = (float)bi;
            sbi = bi;
        }
        __syncthreads();
        if (fused && threadIdx.x < 64)
            outz[(size_t)row * 64 + threadIdx.x] = cb4[(size_t)sbi * 64 + threadIdx.x];
    }
}

__global__ void vq_gather_kernel(const float* __restrict__ cb,
                                 const float* __restrict__ idxF,
                                 float4* __restrict__ out4) {
    int g = blockIdx.x * blockDim.x + threadIdx.x;
    const float4* cb4 = reinterpret_cast<const float4*>(cb);
    for (int i = g; i < NROWS * 64; i += gridDim.x * blockDim.x) {
        int row = i >> 6, q = i & 63;
        int idx = (int)idxF[row];
        out4[i] = cb4[(size_t)idx * 64 + q];
    }
}

extern "C" void kernel_launch(void* const* d_in, const int* in_sizes, int n_in,
                              void* d_out, int out_size, void* d_ws, size_t ws_size,
                              hipStream_t stream) {
    const float* z  = (const float*)d_in[0];
    const float* cb = (const float*)d_in[1];
    float* out = (float*)d_out;

    const int fused = (ws_size >= (size_t)SB_NEED) ? 1 : 0;
    char* SB = fused ? (char*)d_ws : (char*)d_out;

    unsigned short* candp = (unsigned short*)(SB + SB_CAND);
    unsigned*       cntp  = (unsigned*)(SB + SB_CNT);
    float*          zsq   = (float*)(SB + SB_ZSQ);
    float*          csq   = (float*)(SB + SB_CSQ);
    float*          csq1  = (float*)(SB + SB_CSQ1);
    unsigned*       ovl   = (unsigned*)(SB + SB_OVL);
    unsigned*       ovc   = (unsigned*)(SB + SB_OVC);
    char*           cbimg = SB + SB_CBIMG;
    char*           zimg  = SB + SB_ZIMG;
    float*          idxF  = out + 8388608;   // output 1 (indices as float)

    vq_prep_kernel<<<(262144 + 1048576 + KCB + NROWS + 255) / 256, 256, 0, stream>>>(
        z, cb, cbimg, zimg, zsq, csq, csq1, cntp, ovc);
    vq_screen_kernel<<<1024, 256, 0, stream>>>(zimg, cbimg, csq1, cntp, candp);
    vq_exact_kernel<<<NROWS / 4, 256, 0, stream>>>(
        z, cb, zsq, csq, cntp, candp, ovl, ovc, idxF, (float4*)out, fused);
    vq_cleanup_kernel<<<64, 256, 0, stream>>>(
        z, cb, zsq, csq, ovl, ovc, idxF, (float4*)out, fused);
    if (!fused)
        vq_gather_kernel<<<2048, 256, 0, stream>>>(cb, idxF, (float4*)out);
}

// Round 14
// 292.141 us; speedup vs baseline: 440.5670x; 1.4141x over previous
//
#include <hip/hip_runtime.h>

// Vector quantization: z [32768,256] f32, codebook [8192,256] f32
// outputs: z_q [32768,256] f32, indices [32768] (as float)
//
// bf16 MFMA screen (MARGIN=4.5e-4) + exact resolve with the bitwise round-2
// f32 chain (absmax 0 in rounds 2-13).
// Screen v8 = round-10 structure (64 rows/wave, reg-streamed B) + acc
// ping-pong: tile t's epilogue runs with no dependence on tile t+1's MFMA
// chain, so EPI VALU + runmin ds_read hide in MFMA chain bubbles.
// Round-13 lesson: rows/wave is the B-traffic denominator -- keep 64.

#define NROWS 32768
#define DIM   256
#define KCB   8192
#define CANDCAP 128
#define MARGIN  4.5e-4f
#define WBUF    320

// scratch byte offsets (from scratch base SB = d_ws or d_out)
#define SB_CAND  0u          // u16 [32768][128]  8 MB
#define SB_CNT   8388608u    // u32 [32768]
#define SB_ZSQ   8519680u    // f32 [32768]
#define SB_CSQ   8650752u    // f32 [8192]
#define SB_CSQ1  8683520u    // f32 [8192]
#define SB_OVL   8716288u    // u32 [32768]
#define SB_OVC   8847360u    // u32 (+pad)
#define SB_IMG   8847424u    // B tile image [T 512][kk 8][lane 64]x16B = 4 MB
#define SB_NEED  13041728u   // img end

using bf16x8 = __attribute__((ext_vector_type(8))) short;
using f32x4  = __attribute__((ext_vector_type(4))) float;
using u32x4  = __attribute__((ext_vector_type(4))) unsigned int;

__device__ __forceinline__ unsigned short bf16rne(float f) {
    unsigned u = __float_as_uint(f);
    unsigned r = u + 0x7FFFu + ((u >> 16) & 1u);
    return (unsigned short)(r >> 16);
}

__device__ __forceinline__ unsigned pack2_bf16(float a, float b) {
    return (unsigned)bf16rne(a) | ((unsigned)bf16rne(b) << 16);
}

// numpy pairwise sum of squares, n=256, bitwise-faithful (rounds 2-13).
__device__ float np_sumsq_256(const float* __restrict__ p) {
#pragma clang fp contract(off)
    float blk[2];
    #pragma unroll
    for (int b = 0; b < 2; ++b) {
        const float4* q4 = reinterpret_cast<const float4*>(p + b * 128);
        float4 a0 = q4[0], a1 = q4[1];
        float r[8];
        r[0] = __fmul_rn(a0.x, a0.x); r[1] = __fmul_rn(a0.y, a0.y);
        r[2] = __fmul_rn(a0.z, a0.z); r[3] = __fmul_rn(a0.w, a0.w);
        r[4] = __fmul_rn(a1.x, a1.x); r[5] = __fmul_rn(a1.y, a1.y);
        r[6] = __fmul_rn(a1.z, a1.z); r[7] = __fmul_rn(a1.w, a1.w);
        #pragma unroll
        for (int i = 2; i < 32; i += 2) {
            a0 = q4[i]; a1 = q4[i + 1];
            r[0] = __fadd_rn(r[0], __fmul_rn(a0.x, a0.x));
            r[1] = __fadd_rn(r[1], __fmul_rn(a0.y, a0.y));
            r[2] = __fadd_rn(r[2], __fmul_rn(a0.z, a0.z));
            r[3] = __fadd_rn(r[3], __fmul_rn(a0.w, a0.w));
            r[4] = __fadd_rn(r[4], __fmul_rn(a1.x, a1.x));
            r[5] = __fadd_rn(r[5], __fmul_rn(a1.y, a1.y));
            r[6] = __fadd_rn(r[6], __fmul_rn(a1.z, a1.z));
            r[7] = __fadd_rn(r[7], __fmul_rn(a1.w, a1.w));
        }
        blk[b] = __fadd_rn(
            __fadd_rn(__fadd_rn(r[0], r[1]), __fadd_rn(r[2], r[3])),
            __fadd_rn(__fadd_rn(r[4], r[5]), __fadd_rn(r[6], r[7])));
    }
    return __fadd_rn(blk[0], blk[1]);
}

// Fused prep: B tile image convert + csq/csq1 + zsq + counter init.
// B image: [T 512][kk 8][s 64] x 16B; s = lhi*16 + code, content = bf16x8 of
// cb[T*16+code][kk*32+lhi*8 .. +8).
__global__ void vq_prep_kernel(const float* __restrict__ z,
                               const float* __restrict__ cb,
                               char* __restrict__ img,
                               float* __restrict__ zsq, float* __restrict__ csq,
                               float* __restrict__ csq1,
                               unsigned* __restrict__ cnt, unsigned* __restrict__ ovc) {
    int t = blockIdx.x * 256 + threadIdx.x;
    if (t < NROWS) cnt[t] = 0;
    if (t == 0) *ovc = 0;
    if (t < 262144) {
        int s = t & 63, kk = (t >> 6) & 7, T = t >> 9;
        int code = s & 15, lhi = s >> 4;
        const float* src = cb + (size_t)(T * 16 + code) * DIM + kk * 32 + lhi * 8;
        float4 v0 = *reinterpret_cast<const float4*>(src);
        float4 v1 = *reinterpret_cast<const float4*>(src + 4);
        uint4 o;
        o.x = pack2_bf16(v0.x, v0.y); o.y = pack2_bf16(v0.z, v0.w);
        o.z = pack2_bf16(v1.x, v1.y); o.w = pack2_bf16(v1.z, v1.w);
        *reinterpret_cast<uint4*>(img + (size_t)T * 8192 + kk * 1024 + s * 16) = o;
    } else if (t < 262144 + KCB) {
        int k = t - 262144;
        float s = np_sumsq_256(cb + (size_t)k * DIM);
        csq[k] = s;
        csq1[k] = s + 1.0f;
    } else if (t < 262144 + KCB + NROWS) {
        int r = t - 262144 - KCB;
        zsq[r] = np_sumsq_256(z + (size_t)r * DIM);
    }
}

// ---------------- register-streamed MFMA screen, acc ping-pong --------------
// Grid 256 x 512 thr (8 waves = 2 wr x 4 wc). Wave: 64 rows x 2048 codes as
// 128 16-code tiles. B dbuf in named regs; two acc sets so EPI(t) has no
// dependence on MFMA(t+1) and sinks into its chain bubbles.
__global__ __launch_bounds__(512, 2) void vq_screen_kernel(
    const float* __restrict__ z, const char* __restrict__ img,
    const float* __restrict__ csq1,
    unsigned* __restrict__ cnt, unsigned short* __restrict__ cand) {
    __shared__ unsigned runmin[128];
    __shared__ unsigned wcnt[8];
    __shared__ unsigned wbuf[8][WBUF];
    const int tid = threadIdx.x, lane = tid & 63, wid = tid >> 6;
    const int wr = wid >> 2, wc = wid & 3;
    const int l15 = lane & 15, lhi = lane >> 4;
    const int row0 = blockIdx.x * 128;
    const int tbase = wc * 128;

    // A fragments (one-time bf16 convert from raw z)
    bf16x8 ah[4][8];
    #pragma unroll
    for (int m = 0; m < 4; ++m) {
        const float* zr = z + (size_t)(row0 + wr * 64 + m * 16 + l15) * DIM;
        #pragma unroll
        for (int kk = 0; kk < 8; ++kk) {
            float4 v0 = *reinterpret_cast<const float4*>(zr + kk * 32 + lhi * 8);
            float4 v1 = *reinterpret_cast<const float4*>(zr + kk * 32 + lhi * 8 + 4);
            uint4 o;
            o.x = pack2_bf16(v0.x, v0.y); o.y = pack2_bf16(v0.z, v0.w);
            o.z = pack2_bf16(v1.x, v1.y); o.w = pack2_bf16(v1.z, v1.w);
            ah[m][kk] = __builtin_bit_cast(bf16x8, o);
        }
    }

    if (tid < 128) runmin[tid] = 0x7F800000u;   // +inf (s'' > 0 -> uint-monotone)
    if (tid < 8) wcnt[tid] = 0;
    __syncthreads();                            // the only block barrier

    f32x4 aA[4], aB[4];
    #pragma unroll
    for (int m = 0; m < 4; ++m) {
        aA[m] = (f32x4){0.f, 0.f, 0.f, 0.f};
        aB[m] = (f32x4){0.f, 0.f, 0.f, 0.f};
    }

    const char*  gp  = img + (size_t)tbase * 8192 + (size_t)lane * 16;
    const float* cpe = csq1 + tbase * 16 + l15;     // EPI's own csq walker
    int codeb = tbase * 16 + l15;

    u32x4 bA[8], bB[8];

    auto PUSH = [&](int lr, int code) {
        unsigned pi = atomicAdd(&wcnt[wid], 1u);
        if (pi < WBUF) wbuf[wid][pi] = ((unsigned)lr << 13) | (unsigned)code;
        else {
            int grow = row0 + lr;
            unsigned gs = atomicAdd(&cnt[grow], 1u);
            if (gs < CANDCAP) cand[(size_t)grow * CANDCAP + gs] = (unsigned short)code;
        }
    };

#define LOADR(bh)                                                         \
    {                                                                     \
        _Pragma("unroll")                                                 \
        for (int kk = 0; kk < 8; ++kk)                                    \
            bh[kk] = *reinterpret_cast<const u32x4*>(gp + kk * 1024);     \
        gp += 8192;                                                       \
    }

#define MFMAS(bh, a)                                                      \
    {                                                                     \
        _Pragma("unroll")                                                 \
        for (int kk = 0; kk < 8; ++kk) {                                  \
            bf16x8 bv = __builtin_bit_cast(bf16x8, bh[kk]);               \
            _Pragma("unroll")                                             \
            for (int m = 0; m < 4; ++m)                                   \
                a[m] = __builtin_amdgcn_mfma_f32_16x16x32_bf16(           \
                    ah[m][kk], bv, a[m], 0, 0, 0);                        \
        }                                                                 \
    }

#define EPI(a)                                                            \
    {                                                                     \
        const float csv = *cpe; cpe += 16;                                \
        _Pragma("unroll")                                                 \
        for (int m = 0; m < 4; ++m) {                                     \
            const int lr0 = wr * 64 + m * 16 + lhi * 4;                   \
            uint4 rmb = *reinterpret_cast<const uint4*>(&runmin[lr0]);    \
            float s0 = fmaf(a[m][0], -2.0f, csv);                         \
            float s1 = fmaf(a[m][1], -2.0f, csv);                         \
            float s2 = fmaf(a[m][2], -2.0f, csv);                         \
            float s3 = fmaf(a[m][3], -2.0f, csv);                         \
            bool c0 = s0 < __uint_as_float(rmb.x) + MARGIN;               \
            bool c1 = s1 < __uint_as_float(rmb.y) + MARGIN;               \
            bool c2 = s2 < __uint_as_float(rmb.z) + MARGIN;               \
            bool c3 = s3 < __uint_as_float(rmb.w) + MARGIN;               \
            if (__any(c0 | c1 | c2 | c3)) {                               \
                if (c0) { if (s0 < __uint_as_float(rmb.x)) atomicMin(&runmin[lr0 + 0], __float_as_uint(s0)); PUSH(lr0 + 0, codeb); } \
                if (c1) { if (s1 < __uint_as_float(rmb.y)) atomicMin(&runmin[lr0 + 1], __float_as_uint(s1)); PUSH(lr0 + 1, codeb); } \
                if (c2) { if (s2 < __uint_as_float(rmb.z)) atomicMin(&runmin[lr0 + 2], __float_as_uint(s2)); PUSH(lr0 + 2, codeb); } \
                if (c3) { if (s3 < __uint_as_float(rmb.w)) atomicMin(&runmin[lr0 + 3], __float_as_uint(s3)); PUSH(lr0 + 3, codeb); } \
            }                                                             \
            a[m] = (f32x4){0.f, 0.f, 0.f, 0.f};                           \
        }                                                                 \
        codeb += 16;                                                      \
    }

    // prologue: tiles 0,1,2 loaded; 0,1 mfma'd; 0 epi'd (self-bound)
    LOADR(bA);                       // tile 0
    LOADR(bB);                       // tile 1
    MFMAS(bA, aA);                   // tile 0
    LOADR(bA);                       // tile 2
    MFMAS(bB, aB);                   // tile 1
    {   // tile 0 epilogue: self-bound (runmin may still be +inf)
        const float csv = *cpe; cpe += 16;
        #pragma unroll
        for (int m = 0; m < 4; ++m) {
            const int lr0 = wr * 64 + m * 16 + lhi * 4;
            #pragma unroll
            for (int r = 0; r < 4; ++r) {
                float s2 = fmaf(aA[m][r], -2.0f, csv);
                float sm = s2;
                sm = fminf(sm, __shfl_xor(sm, 1));
                sm = fminf(sm, __shfl_xor(sm, 2));
                sm = fminf(sm, __shfl_xor(sm, 4));
                sm = fminf(sm, __shfl_xor(sm, 8));
                if (l15 == 0) atomicMin(&runmin[lr0 + r], __float_as_uint(sm));
                if (s2 < sm + MARGIN) PUSH(lr0 + r, codeb);
            }
            aA[m] = (f32x4){0.f, 0.f, 0.f, 0.f};
        }
        codeb += 16;
    }

    // steady state: iter i (1..62): loads 2i+1,2i+2; mfma 2i,2i+1; epi 2i-1,2i
    for (int i = 1; i <= 62; ++i) {
        LOADR(bB);  MFMAS(bA, aA);  EPI(aB);
        LOADR(bA);  MFMAS(bB, aB);  EPI(aA);
    }
    // tail: loaded 126; mfma'd 125; epi'd 124
    LOADR(bB);  MFMAS(bA, aA);  EPI(aB);   // load 127, mfma 126, epi 125
    MFMAS(bB, aB);  EPI(aA);               // mfma 127, epi 126
    EPI(aB);                               // epi 127

    // flush wave-local candidate buffer to global per-row lists
    unsigned n = wcnt[wid]; if (n > WBUF) n = WBUF;
    for (unsigned e = lane; e < n; e += 64) {
        unsigned u = wbuf[wid][e];
        int row = row0 + (int)(u >> 13);
        int code = (int)(u & 8191u);
        unsigned slot = atomicAdd(&cnt[row], 1u);
        if (slot < CANDCAP) cand[(size_t)row * CANDCAP + slot] = (unsigned short)code;
    }
#undef LOADR
#undef MFMAS
#undef EPI
}

// ---------------- exact resolve (rounds 6-13 chain) + fused gather ----------
__global__ __launch_bounds__(256) void vq_exact_kernel(
    const float* __restrict__ z, const float* __restrict__ cb,
    const float* __restrict__ zsq, const float* __restrict__ csq,
    const unsigned* __restrict__ cnt, const unsigned short* __restrict__ cand,
    unsigned* __restrict__ ovl, unsigned* __restrict__ ovc,
    float* __restrict__ idxF, float4* __restrict__ outz, int fused) {
    __shared__ float zrow[4][DIM];
    const int wid = threadIdx.x >> 6, lane = threadIdx.x & 63;
    const int row = blockIdx.x * 4 + wid;

    float4 zv4 = *reinterpret_cast<const float4*>(&z[(size_t)row * DIM + lane * 4]);
    *reinterpret_cast<float4*>(&zrow[wid][lane * 4]) = zv4;
    __syncthreads();

    const unsigned c = cnt[row];
    if (c == 0 || c > CANDCAP) {
        if (lane == 0) { unsigned s = atomicAdd(ovc, 1u); ovl[s] = row; }
        return;
    }

    const float Zr = zsq[row];
    const float4* cb4 = reinterpret_cast<const float4*>(cb);
    float best = 3.4e38f;
    int   bi   = 0x7FFFFFFF;

    for (int j = lane; j < (int)c; j += 64) {
        int k = cand[(size_t)row * CANDCAP + j];
        float a = 0.0f;
        #pragma unroll 8
        for (int q = 0; q < 64; ++q) {
            float4 cv = cb4[(size_t)k * 64 + q];
            float4 zv = *reinterpret_cast<const float4*>(&zrow[wid][q * 4]);
            a = fmaf(zv.x, cv.x, a); a = fmaf(zv.y, cv.y, a);
            a = fmaf(zv.z, cv.z, a); a = fmaf(zv.w, cv.w, a);
        }
        float sv = __fadd_rn(__fsub_rn(Zr, __fmul_rn(2.0f, a)), csq[k]);
        if (sv < best || (sv == best && k < bi)) { best = sv; bi = k; }
    }
    #pragma unroll
    for (int mk = 32; mk >= 1; mk >>= 1) {
        float ov = __shfl_xor(best, mk);
        int   oi = __shfl_xor(bi, mk);
        if (ov < best || (ov == best && oi < bi)) { best = ov; bi = oi; }
    }
    if (lane == 0) idxF[row] = (float)bi;
    if (fused) outz[(size_t)row * 64 + lane] = cb4[(size_t)bi * 64 + lane];
}

// Full scan for overflow rows (expected 0). Bitwise chain, first-index ties.
__global__ __launch_bounds__(256) void vq_cleanup_kernel(
    const float* __restrict__ z, const float* __restrict__ cb,
    const float* __restrict__ zsq, const float* __restrict__ csq,
    const unsigned* __restrict__ ovl, const unsigned* __restrict__ ovc,
    float* __restrict__ idxF, float4* __restrict__ outz, int fused) {
    __shared__ float zrow[DIM];
    __shared__ float wv[4]; __shared__ int wi[4];
    __shared__ int sbi;
    const int lane = threadIdx.x & 63, wid = threadIdx.x >> 6;
    const unsigned count = *ovc;
    for (unsigned w = blockIdx.x; w < count; w += gridDim.x) {
        const int row = ovl[w];
        __syncthreads();
        *reinterpret_cast<float4*>(&zrow[threadIdx.x * 4 & (DIM - 1)]) =
            *reinterpret_cast<const float4*>(&z[(size_t)row * DIM + (threadIdx.x * 4 & (DIM - 1))]);
        __syncthreads();
        const float Zr = zsq[row];
        const float4* cb4 = reinterpret_cast<const float4*>(cb);
        float best = 3.4e38f; int bi = 0x7FFFFFFF;
        for (int k = threadIdx.x; k < KCB; k += 256) {
            float a = 0.0f;
            #pragma unroll 8
            for (int q = 0; q < 64; ++q) {
                float4 cv = cb4[(size_t)k * 64 + q];
                float4 zv = *reinterpret_cast<const float4*>(&zrow[q * 4]);
                a = fmaf(zv.x, cv.x, a); a = fmaf(zv.y, cv.y, a);
                a = fmaf(zv.z, cv.z, a); a = fmaf(zv.w, cv.w, a);
            }
            float sv = __fadd_rn(__fsub_rn(Zr, __fmul_rn(2.0f, a)), csq[k]);
            if (sv < best || (sv == best && k < bi)) { best = sv; bi = k; }
        }
        #pragma unroll
        for (int mk = 32; mk >= 1; mk >>= 1) {
            float ov = __shfl_xor(best, mk);
            int   oi = __shfl_xor(bi, mk);
            if (ov < best || (ov == best && oi < bi)) { best = ov; bi = oi; }
        }
        if (lane == 0) { wv[wid] = best; wi[wid] = bi; }
        __syncthreads();
        if (threadIdx.x == 0) {
            #pragma unroll
            for (int u = 1; u < 4; ++u)
                if (wv[u] < best || (wv[u] == best && wi[u] < bi)) { best = wv[u]; bi = wi[u]; }
            idxF[row] = (float)bi;
            sbi = bi;
        }
        __syncthreads();
        if (fused && threadIdx.x < 64)
            outz[(size_t)row * 64 + threadIdx.x] = cb4[(size_t)sbi * 64 + threadIdx.x];
    }
}

__global__ void vq_gather_kernel(const float* __restrict__ cb,
                                 const float* __restrict__ idxF,
                                 float4* __restrict__ out4) {
    int g = blockIdx.x * blockDim.x + threadIdx.x;
    const float4* cb4 = reinterpret_cast<const float4*>(cb);
    for (int i = g; i < NROWS * 64; i += gridDim.x * blockDim.x) {
        int row = i >> 6, q = i & 63;
        int idx = (int)idxF[row];
        out4[i] = cb4[(size_t)idx * 64 + q];
    }
}

extern "C" void kernel_launch(void* const* d_in, const int* in_sizes, int n_in,
                              void* d_out, int out_size, void* d_ws, size_t ws_size,
                              hipStream_t stream) {
    const float* z  = (const float*)d_in[0];
    const float* cb = (const float*)d_in[1];
    float* out = (float*)d_out;

    const int fused = (ws_size >= (size_t)SB_NEED) ? 1 : 0;
    char* SB = fused ? (char*)d_ws : (char*)d_out;

    unsigned short* candp = (unsigned short*)(SB + SB_CAND);
    unsigned*       cntp  = (unsigned*)(SB + SB_CNT);
    float*          zsq   = (float*)(SB + SB_ZSQ);
    float*          csq   = (float*)(SB + SB_CSQ);
    float*          csq1  = (float*)(SB + SB_CSQ1);
    unsigned*       ovl   = (unsigned*)(SB + SB_OVL);
    unsigned*       ovc   = (unsigned*)(SB + SB_OVC);
    char*           img   = SB + SB_IMG;
    float*          idxF  = out + 8388608;   // output 1 (indices as float)

    vq_prep_kernel<<<(262144 + KCB + NROWS + 255) / 256, 256, 0, stream>>>(
        z, cb, img, zsq, csq, csq1, cntp, ovc);
    vq_screen_kernel<<<NROWS / 128, 512, 0, stream>>>(z, img, csq1, cntp, candp);
    vq_exact_kernel<<<NROWS / 4, 256, 0, stream>>>(
        z, cb, zsq, csq, cntp, candp, ovl, ovc, idxF, (float4*)out, fused);
    vq_cleanup_kernel<<<64, 256, 0, stream>>>(
        z, cb, zsq, csq, ovl, ovc, idxF, (float4*)out, fused);
    if (!fused)
        vq_gather_kernel<<<2048, 256, 0, stream>>>(cb, idxF, (float4*)out);
}